// Round 1
// baseline (1507.262 us; speedup 1.0000x reference)
//
#include <hip/hip_runtime.h>

// GCN layer: out = D^-1/2 (A + I) D^-1/2 (x @ kernel) + bias
// N=100000 nodes, E=1600000 edges, F=U=64, fp32.

#define FILL_WEIGHT 1.0f

__global__ void k_init_deg(float* __restrict__ deg, int n, float fill) {
    int i = blockIdx.x * blockDim.x + threadIdx.x;
    if (i < n) deg[i] = fill;
}

__global__ void k_deg_edges(const int* __restrict__ row, const float* __restrict__ w,
                            float* __restrict__ deg, int E) {
    int e = blockIdx.x * blockDim.x + threadIdx.x;
    if (e < E) atomicAdd(&deg[row[e]], w[e]);
}

__global__ void k_dis(const float* __restrict__ deg, float* __restrict__ dis, int n) {
    int i = blockIdx.x * blockDim.x + threadIdx.x;
    if (i < n) {
        float d = deg[i];
        dis[i] = (d > 0.f) ? rsqrtf(fmaxf(d, 1e-12f)) : 0.f;
    }
}

// h = x @ kernel.  Block = 256 threads = 4 rows x 64 units.
// kernel (64x64 f32 = 16 KB) staged in LDS; 4 x-rows staged in LDS.
__global__ __launch_bounds__(256) void k_gemm(const float* __restrict__ x,
                                              const float* __restrict__ kern,
                                              float* __restrict__ h, int n) {
    __shared__ float ks[64 * 64];
    __shared__ float xs[4 * 64];
    int tid = threadIdx.x;
    #pragma unroll
    for (int i = 0; i < 16; ++i) ks[tid + i * 256] = kern[tid + i * 256];

    int r0 = blockIdx.x * 4;
    int idx = r0 * 64 + tid;
    xs[tid] = (idx < n * 64) ? x[idx] : 0.f;
    __syncthreads();

    int r = tid >> 6;     // 0..3 local row
    int u = tid & 63;     // unit
    int rowi = r0 + r;
    if (rowi < n) {
        float acc = 0.f;
        #pragma unroll
        for (int k = 0; k < 64; ++k)
            acc = fmaf(xs[r * 64 + k], ks[k * 64 + u], acc);
        h[rowi * 64 + u] = acc;
    }
}

// out[i][u] = dis[i]^2 * fill * h[i][u] + bias[u]   (self-loop term + bias)
__global__ void k_out_init(const float* __restrict__ h, const float* __restrict__ dis,
                           const float* __restrict__ bias, float* __restrict__ out,
                           int n, float fill) {
    int t = blockIdx.x * blockDim.x + threadIdx.x;
    if (t < n * 64) {
        int i = t >> 6, u = t & 63;
        float s = dis[i];
        out[t] = s * s * fill * h[t] + bias[u];
    }
}

// out[row[e]] += dis[row]*w*dis[col] * h[col[e]] ; 16 threads/edge, float4/lane
__global__ __launch_bounds__(256) void k_scatter(const int* __restrict__ row,
                                                 const int* __restrict__ col,
                                                 const float* __restrict__ w,
                                                 const float* __restrict__ dis,
                                                 const float* __restrict__ h,
                                                 float* __restrict__ out, int E) {
    long long t = (long long)blockIdx.x * blockDim.x + threadIdx.x;
    int e = (int)(t >> 4);
    int j = (int)(t & 15);
    if (e < E) {
        int r = row[e], c = col[e];
        float nw = dis[r] * w[e] * dis[c];
        float4 hv = reinterpret_cast<const float4*>(h + (long long)c * 64)[j];
        float* op = out + (long long)r * 64 + j * 4;
        atomicAdd(op + 0, hv.x * nw);
        atomicAdd(op + 1, hv.y * nw);
        atomicAdd(op + 2, hv.z * nw);
        atomicAdd(op + 3, hv.w * nw);
    }
}

extern "C" void kernel_launch(void* const* d_in, const int* in_sizes, int n_in,
                              void* d_out, int out_size, void* d_ws, size_t ws_size,
                              hipStream_t stream) {
    const float* x    = (const float*)d_in[0];
    const int*   ei   = (const int*)d_in[1];
    const float* ew   = (const float*)d_in[2];
    const float* kern = (const float*)d_in[3];
    const float* bias = (const float*)d_in[4];
    float* out = (float*)d_out;

    int N = in_sizes[0] / 64;
    int E = in_sizes[1] / 2;
    const int* row = ei;
    const int* col = ei + E;

    float* deg = (float*)d_ws;          // N floats
    float* dis = deg + N;               // N floats
    float* h   = dis + N;               // N*64 floats

    const int B = 256;

    k_init_deg<<<(N + B - 1) / B, B, 0, stream>>>(deg, N, FILL_WEIGHT);
    k_deg_edges<<<(E + B - 1) / B, B, 0, stream>>>(row, ew, deg, E);
    k_dis<<<(N + B - 1) / B, B, 0, stream>>>(deg, dis, N);
    k_gemm<<<(N + 3) / 4, B, 0, stream>>>(x, kern, h, N);
    k_out_init<<<((long long)N * 64 + B - 1) / B, B, 0, stream>>>(h, dis, bias, out, N, FILL_WEIGHT);
    long long st = (long long)E * 16;
    k_scatter<<<(st + B - 1) / B, B, 0, stream>>>(row, col, ew, dis, h, out, E);
}

// Round 2
// 317.807 us; speedup vs baseline: 4.7427x; 4.7427x over previous
//
#include <hip/hip_runtime.h>

// GCN layer: out = D^-1/2 (A + I) D^-1/2 (x @ kernel) + bias
// N=100000, E=1600000, F=U=64, fp32.
// Strategy: device-side counting sort of edges by destination (row), then
// atomic-free "pull" aggregation: one 64-lane wave per destination node.

typedef unsigned long long u64;
#define FILL 1.0f

// ---------------- sort phase ----------------

__global__ void k_zero(int* __restrict__ p, int n) {
    int i = blockIdx.x * blockDim.x + threadIdx.x;
    if (i < n) p[i] = 0;
}

__global__ void k_hist(const int* __restrict__ row, int* __restrict__ cnt, int E) {
    int e = blockIdx.x * blockDim.x + threadIdx.x;
    if (e < E) atomicAdd(&cnt[row[e]], 1);
}

__global__ __launch_bounds__(256) void k_chunk_sum(const int* __restrict__ cnt,
                                                   int* __restrict__ partial, int N) {
    __shared__ int s[256];
    int t = threadIdx.x, i = blockIdx.x * 256 + t;
    s[t] = (i < N) ? cnt[i] : 0;
    __syncthreads();
    for (int o = 128; o > 0; o >>= 1) {
        if (t < o) s[t] += s[t + o];
        __syncthreads();
    }
    if (t == 0) partial[blockIdx.x] = s[0];
}

__global__ __launch_bounds__(512) void k_scan_partials(int* __restrict__ partial, int n) {
    __shared__ int a[512], b[512];
    int t = threadIdx.x;
    a[t] = (t < n) ? partial[t] : 0;
    __syncthreads();
    int *src = a, *dst = b;
    for (int o = 1; o < 512; o <<= 1) {
        int v = src[t];
        if (t >= o) v += src[t - o];
        dst[t] = v;
        __syncthreads();
        int* tmp = src; src = dst; dst = tmp;
    }
    if (t < n) partial[t] = t ? src[t - 1] : 0;   // exclusive
}

__global__ __launch_bounds__(256) void k_chunk_scan(const int* __restrict__ cnt,
                                                    const int* __restrict__ partial,
                                                    int* __restrict__ start,
                                                    int* __restrict__ cur, int N) {
    __shared__ int a[256], bsh[256];
    int t = threadIdx.x, i = blockIdx.x * 256 + t;
    int c = (i < N) ? cnt[i] : 0;
    a[t] = c;
    __syncthreads();
    int *src = a, *dst = bsh;
    for (int o = 1; o < 256; o <<= 1) {
        int v = src[t];
        if (t >= o) v += src[t - o];
        dst[t] = v;
        __syncthreads();
        int* tmp = src; src = dst; dst = tmp;
    }
    int incl = src[t];
    int base = partial[blockIdx.x];
    if (i < N) {
        int s0 = base + incl - c;
        start[i] = s0;
        cur[i] = s0;
        if (i == N - 1) start[N] = base + incl;   // == E
    }
}

__global__ void k_build(const int* __restrict__ row, const int* __restrict__ col,
                        const float* __restrict__ w, int* __restrict__ cur,
                        u64* __restrict__ edges, int E) {
    int e = blockIdx.x * blockDim.x + threadIdx.x;
    if (e < E) {
        int r = row[e];
        int pos = atomicAdd(&cur[r], 1);
        edges[pos] = (u64)(unsigned)col[e] | ((u64)__float_as_uint(w[e]) << 32);
    }
}

// dis[i] = rsqrt(FILL + sum of w over incoming segment)
__global__ void k_seg_dis(const int* __restrict__ start, const u64* __restrict__ edges,
                          float* __restrict__ dis, int N) {
    int i = blockIdx.x * blockDim.x + threadIdx.x;
    if (i < N) {
        int s = start[i], epos = start[i + 1];
        float d = FILL;
        for (int e = s; e < epos; ++e)
            d += __uint_as_float((unsigned)(edges[e] >> 32));
        dis[i] = (d > 0.f) ? rsqrtf(fmaxf(d, 1e-12f)) : 0.f;
    }
}

// ---------------- h2 = dis[r] * (x @ kernel) ----------------
// block: 32 rows x 64 units; thread: 2 rows x 4 units.
__global__ __launch_bounds__(256) void k_gemm(const float* __restrict__ x,
                                              const float* __restrict__ kern,
                                              const float* __restrict__ dis,
                                              float* __restrict__ h2, int n) {
    __shared__ __align__(16) float ks[64 * 64];
    __shared__ float xs[32 * 65];   // pad 1 -> conflict-free scalar reads
    int t = threadIdx.x;

    const float4* k4 = (const float4*)kern;
    float4* ks4 = (float4*)ks;
    #pragma unroll
    for (int i = 0; i < 4; ++i) ks4[t + i * 256] = k4[t + i * 256];

    int r0 = blockIdx.x * 32;
    #pragma unroll
    for (int p = 0; p < 2; ++p) {
        int rr = (t >> 4) + p * 16;
        int cc = (t & 15) * 4;
        int gr = r0 + rr;
        float4 xv = make_float4(0.f, 0.f, 0.f, 0.f);
        if (gr < n) xv = *(const float4*)(x + (size_t)gr * 64 + cc);
        xs[rr * 65 + cc + 0] = xv.x;
        xs[rr * 65 + cc + 1] = xv.y;
        xs[rr * 65 + cc + 2] = xv.z;
        xs[rr * 65 + cc + 3] = xv.w;
    }
    __syncthreads();

    int rg = t >> 4;        // 0..15 -> rows 2rg, 2rg+1
    int ug = t & 15;        // units 4ug..4ug+3
    int ra = 2 * rg, rb = 2 * rg + 1;
    float4 a0 = make_float4(0.f, 0.f, 0.f, 0.f);
    float4 a1 = make_float4(0.f, 0.f, 0.f, 0.f);
    #pragma unroll
    for (int k = 0; k < 64; ++k) {
        float xa = xs[ra * 65 + k];
        float xb = xs[rb * 65 + k];
        float4 kv = *(const float4*)(ks + k * 64 + 4 * ug);
        a0.x = fmaf(xa, kv.x, a0.x); a0.y = fmaf(xa, kv.y, a0.y);
        a0.z = fmaf(xa, kv.z, a0.z); a0.w = fmaf(xa, kv.w, a0.w);
        a1.x = fmaf(xb, kv.x, a1.x); a1.y = fmaf(xb, kv.y, a1.y);
        a1.z = fmaf(xb, kv.z, a1.z); a1.w = fmaf(xb, kv.w, a1.w);
    }
    int gra = r0 + ra, grb = r0 + rb;
    if (gra < n) {
        float d = dis[gra];
        float4 o = make_float4(d * a0.x, d * a0.y, d * a0.z, d * a0.w);
        *(float4*)(h2 + (size_t)gra * 64 + 4 * ug) = o;
    }
    if (grb < n) {
        float d = dis[grb];
        float4 o = make_float4(d * a1.x, d * a1.y, d * a1.z, d * a1.w);
        *(float4*)(h2 + (size_t)grb * 64 + 4 * ug) = o;
    }
}

// ---------------- pull: one wave per node ----------------
// out[i][u] = dis[i]*( sum_e w_e*h2[c_e][u] + FILL*h2[i][u] ) + bias[u]
__global__ __launch_bounds__(256) void k_pull(const int* __restrict__ start,
                                              const u64* __restrict__ edges,
                                              const float* __restrict__ h2,
                                              const float* __restrict__ dis,
                                              const float* __restrict__ bias,
                                              float* __restrict__ out, int N) {
    int node = (blockIdx.x << 2) + (threadIdx.x >> 6);
    int lane = threadIdx.x & 63;
    if (node >= N) return;
    int s = start[node], epos = start[node + 1];
    float acc = 0.f;
    for (int base = s; base < epos; base += 64) {
        int n = epos - base;
        if (n > 64) n = 64;
        int cl = 0; int vl = 0;
        if (lane < n) {
            u64 p = edges[base + lane];
            cl = (int)(unsigned)p;
            vl = (int)(unsigned)(p >> 32);
        }
        int j = 0;
        for (; j + 4 <= n; j += 4) {
            int c0 = __shfl(cl, j),     c1 = __shfl(cl, j + 1);
            int c2 = __shfl(cl, j + 2), c3 = __shfl(cl, j + 3);
            float v0 = __uint_as_float((unsigned)__shfl(vl, j));
            float v1 = __uint_as_float((unsigned)__shfl(vl, j + 1));
            float v2 = __uint_as_float((unsigned)__shfl(vl, j + 2));
            float v3 = __uint_as_float((unsigned)__shfl(vl, j + 3));
            float g0 = h2[(size_t)c0 * 64 + lane];
            float g1 = h2[(size_t)c1 * 64 + lane];
            float g2 = h2[(size_t)c2 * 64 + lane];
            float g3 = h2[(size_t)c3 * 64 + lane];
            acc = fmaf(v0, g0, acc);
            acc = fmaf(v1, g1, acc);
            acc = fmaf(v2, g2, acc);
            acc = fmaf(v3, g3, acc);
        }
        for (; j < n; ++j) {
            int c = __shfl(cl, j);
            float v = __uint_as_float((unsigned)__shfl(vl, j));
            acc = fmaf(v, h2[(size_t)c * 64 + lane], acc);
        }
    }
    float di = dis[node];
    out[(size_t)node * 64 + lane] =
        di * acc + FILL * di * h2[(size_t)node * 64 + lane] + bias[lane];
}

// ---------------- fallback (atomic scatter, round-1 style) ----------------

__global__ void k_fb_deg_init(float* __restrict__ deg, int n) {
    int i = blockIdx.x * blockDim.x + threadIdx.x;
    if (i < n) deg[i] = FILL;
}
__global__ void k_fb_deg_edges(const int* __restrict__ row, const float* __restrict__ w,
                               float* __restrict__ deg, int E) {
    int e = blockIdx.x * blockDim.x + threadIdx.x;
    if (e < E) atomicAdd(&deg[row[e]], w[e]);
}
__global__ void k_fb_dis(const float* __restrict__ deg, float* __restrict__ dis, int n) {
    int i = blockIdx.x * blockDim.x + threadIdx.x;
    if (i < n) {
        float d = deg[i];
        dis[i] = (d > 0.f) ? rsqrtf(fmaxf(d, 1e-12f)) : 0.f;
    }
}
__global__ void k_fb_outinit(const float* __restrict__ h2, const float* __restrict__ dis,
                             const float* __restrict__ bias, float* __restrict__ out, int n) {
    int t = blockIdx.x * blockDim.x + threadIdx.x;
    if (t < n * 64) {
        int i = t >> 6, u = t & 63;
        out[t] = FILL * dis[i] * h2[t] + bias[u];
    }
}
__global__ __launch_bounds__(256) void k_fb_scatter(const int* __restrict__ row,
                                                    const int* __restrict__ col,
                                                    const float* __restrict__ w,
                                                    const float* __restrict__ dis,
                                                    const float* __restrict__ h2,
                                                    float* __restrict__ out, int E) {
    long long t = (long long)blockIdx.x * blockDim.x + threadIdx.x;
    int e = (int)(t >> 4);
    int j = (int)(t & 15);
    if (e < E) {
        int r = row[e], c = col[e];
        float nw = dis[r] * w[e];
        float4 hv = reinterpret_cast<const float4*>(h2 + (long long)c * 64)[j];
        float* op = out + (long long)r * 64 + j * 4;
        atomicAdd(op + 0, hv.x * nw);
        atomicAdd(op + 1, hv.y * nw);
        atomicAdd(op + 2, hv.z * nw);
        atomicAdd(op + 3, hv.w * nw);
    }
}

// ---------------- launch ----------------

extern "C" void kernel_launch(void* const* d_in, const int* in_sizes, int n_in,
                              void* d_out, int out_size, void* d_ws, size_t ws_size,
                              hipStream_t stream) {
    const float* x    = (const float*)d_in[0];
    const int*   ei   = (const int*)d_in[1];
    const float* ew   = (const float*)d_in[2];
    const float* kern = (const float*)d_in[3];
    const float* bias = (const float*)d_in[4];
    float* out = (float*)d_out;

    int N = in_sizes[0] / 64;
    int E = in_sizes[1] / 2;
    const int* row = ei;
    const int* col = ei + E;

    const int B = 256;
    int nChunks = (N + 255) / 256;

    size_t need = (size_t)E * 8               // edges (packed col,w)
                + (size_t)N * 64 * 4          // h2
                + (size_t)N * 4               // dis
                + (size_t)N * 4               // cnt
                + (size_t)(N + 1) * 4         // start
                + (size_t)N * 4               // cur
                + 512 * 4;                    // partial

    if (ws_size >= need && nChunks <= 512) {
        char* p = (char*)d_ws;
        u64*   edges = (u64*)p;            p += (size_t)E * 8;
        float* h2    = (float*)p;          p += (size_t)N * 64 * 4;
        float* dis   = (float*)p;          p += (size_t)N * 4;
        int*   cnt   = (int*)p;            p += (size_t)N * 4;
        int*   start = (int*)p;            p += (size_t)(N + 1) * 4;
        int*   cur   = (int*)p;            p += (size_t)N * 4;
        int*   partial = (int*)p;

        k_zero<<<(N + B - 1) / B, B, 0, stream>>>(cnt, N);
        k_hist<<<(E + B - 1) / B, B, 0, stream>>>(row, cnt, E);
        k_chunk_sum<<<nChunks, 256, 0, stream>>>(cnt, partial, N);
        k_scan_partials<<<1, 512, 0, stream>>>(partial, nChunks);
        k_chunk_scan<<<nChunks, 256, 0, stream>>>(cnt, partial, start, cur, N);
        k_build<<<(E + B - 1) / B, B, 0, stream>>>(row, col, ew, cur, edges, E);
        k_seg_dis<<<(N + B - 1) / B, B, 0, stream>>>(start, edges, dis, N);
        k_gemm<<<(N + 31) / 32, 256, 0, stream>>>(x, kern, dis, h2, N);
        k_pull<<<(N + 3) / 4, 256, 0, stream>>>(start, edges, h2, dis, bias, out, N);
    } else {
        // fallback: atomic scatter (round-1 path)
        char* p = (char*)d_ws;
        float* h2  = (float*)p;  p += (size_t)N * 64 * 4;
        float* deg = (float*)p;  p += (size_t)N * 4;
        float* dis = (float*)p;

        k_fb_deg_init<<<(N + B - 1) / B, B, 0, stream>>>(deg, N);
        k_fb_deg_edges<<<(E + B - 1) / B, B, 0, stream>>>(row, ew, deg, E);
        k_fb_dis<<<(N + B - 1) / B, B, 0, stream>>>(deg, dis, N);
        k_gemm<<<(N + 31) / 32, 256, 0, stream>>>(x, kern, dis, h2, N);
        k_fb_outinit<<<((long long)N * 64 + B - 1) / B, B, 0, stream>>>(h2, dis, bias, out, N);
        long long st = (long long)E * 16;
        k_fb_scatter<<<(st + B - 1) / B, B, 0, stream>>>(row, col, ew, dis, h2, out, E);
    }
}

// Round 3
// 194.326 us; speedup vs baseline: 7.7564x; 1.6354x over previous
//
#include <hip/hip_runtime.h>

// GCN layer: out = D^-1/2 (A + I) D^-1/2 (x @ kernel) + bias
// N=100000, E=1600000, F=U=64, fp32.
// Pipeline: two-level counting sort by destination (bucket=row>>8, then exact),
// then atomic-free pull aggregation (one wave per destination node).

typedef unsigned long long u64;
#define FILL 1.0f
#define SB 8                      // log2(nodes per bucket)
#define BKN 256                   // nodes per bucket
#define EPT 16                    // edges per thread per scatter tile (tile = 4096)

// ---------------- phase 1: bucket histogram + scan ----------------

__global__ void k_zero(int* __restrict__ p, int n) {
    int i = blockIdx.x * blockDim.x + threadIdx.x;
    if (i < n) p[i] = 0;
}

__global__ __launch_bounds__(256) void k_bhist(const int* __restrict__ row,
                                               int* __restrict__ bcnt, int E, int NB) {
    __shared__ int h[512];
    for (int i = threadIdx.x; i < NB; i += 256) h[i] = 0;
    __syncthreads();
    int stride = gridDim.x * 256;
    for (int e = blockIdx.x * 256 + threadIdx.x; e < E; e += stride)
        atomicAdd(&h[row[e] >> SB], 1);
    __syncthreads();
    for (int i = threadIdx.x; i < NB; i += 256)
        if (h[i]) atomicAdd(&bcnt[i], h[i]);
}

__global__ __launch_bounds__(512) void k_bscan(const int* __restrict__ bcnt,
                                               int* __restrict__ bstart, int* __restrict__ bcur,
                                               int* __restrict__ start, int NB, int N, int E) {
    __shared__ int a[512], bsh[512];
    int t = threadIdx.x;
    a[t] = (t < NB) ? bcnt[t] : 0;
    __syncthreads();
    int *src = a, *dst = bsh;
    for (int o = 1; o < 512; o <<= 1) {
        int v = src[t];
        if (t >= o) v += src[t - o];
        dst[t] = v;
        __syncthreads();
        int* tm = src; src = dst; dst = tm;
    }
    int incl = src[t];
    if (t < NB) {
        int excl = incl - bcnt[t];
        bstart[t] = excl;
        bcur[t] = excl;
    }
    if (t == NB - 1) bstart[NB] = incl;   // == E
    if (t == 0) start[N] = E;
}

// ---------------- phase 2: tile-reserved bucket scatter ----------------
// record: w(bits 63..32) | row_local(31..24) | col(23..0)

__global__ __launch_bounds__(256) void k_bscatter(const int* __restrict__ row,
                                                  const int* __restrict__ col,
                                                  const float* __restrict__ w,
                                                  int* __restrict__ bcur,
                                                  u64* __restrict__ eA, int E, int NB) {
    __shared__ int cnt[512];
    __shared__ int ofs[512];
    int nt = (E + 4095) >> 12;
    for (int tile = blockIdx.x; tile < nt; tile += gridDim.x) {
        int base = tile << 12;
        for (int i = threadIdx.x; i < NB; i += 256) cnt[i] = 0;
        __syncthreads();
        int bk[EPT]; u64 rec[EPT];
        #pragma unroll
        for (int k = 0; k < EPT; ++k) {
            int e = base + threadIdx.x + (k << 8);
            bk[k] = -1;
            if (e < E) {
                int r = row[e];
                bk[k] = r >> SB;
                rec[k] = ((u64)__float_as_uint(w[e]) << 32)
                       | ((u64)(unsigned)(r & (BKN - 1)) << 24)
                       | (u64)(unsigned)col[e];
                atomicAdd(&cnt[bk[k]], 1);
            }
        }
        __syncthreads();
        for (int i = threadIdx.x; i < NB; i += 256) {
            int c = cnt[i];
            ofs[i] = c ? atomicAdd(&bcur[i], c) : 0;
            cnt[i] = 0;        // reuse as running offset within tile
        }
        __syncthreads();
        #pragma unroll
        for (int k = 0; k < EPT; ++k) {
            if (bk[k] >= 0) {
                int pos = ofs[bk[k]] + atomicAdd(&cnt[bk[k]], 1);
                eA[pos] = rec[k];
            }
        }
        __syncthreads();
    }
}

// ---------------- phase 3: exact sort within bucket + start + dis ----------------

__global__ __launch_bounds__(256) void k_fine(const int* __restrict__ bstart,
                                              const u64* __restrict__ eA,
                                              u64* __restrict__ eB,
                                              int* __restrict__ start,
                                              float* __restrict__ dis, int N) {
    __shared__ int ncnt[256];
    __shared__ float degs[256];
    __shared__ int sa[256], sb[256];
    int b = blockIdx.x;
    int s = bstart[b], e1 = bstart[b + 1];
    int cnt = e1 - s;
    int t = threadIdx.x;
    ncnt[t] = 0;
    degs[t] = 0.f;
    __syncthreads();
    for (int i = t; i < cnt; i += 256) {
        u64 p = eA[s + i];
        int rl = (int)((p >> 24) & 0xFF);
        atomicAdd(&ncnt[rl], 1);
        atomicAdd(&degs[rl], __uint_as_float((unsigned)(p >> 32)));
    }
    __syncthreads();
    int c = ncnt[t];
    sa[t] = c;
    __syncthreads();
    int *src = sa, *dst = sb;
    for (int o = 1; o < 256; o <<= 1) {
        int v = src[t];
        if (t >= o) v += src[t - o];
        dst[t] = v;
        __syncthreads();
        int* tm = src; src = dst; dst = tm;
    }
    int excl = src[t] - c;
    int node = (b << SB) + t;
    if (node < N) {
        start[node] = s + excl;
        float d = FILL + degs[t];
        dis[node] = (d > 0.f) ? rsqrtf(fmaxf(d, 1e-12f)) : 0.f;
    }
    ncnt[t] = excl;    // reuse as within-bucket cursor
    __syncthreads();
    for (int i = t; i < cnt; i += 256) {
        u64 p = eA[s + i];
        int rl = (int)((p >> 24) & 0xFF);
        int pos = atomicAdd(&ncnt[rl], 1);
        eB[s + pos] = p & 0xFFFFFFFF00FFFFFFULL;   // keep w | col
    }
}

// ---------------- h2 = dis[r] * (x @ kernel) ----------------

__global__ __launch_bounds__(256) void k_gemm(const float* __restrict__ x,
                                              const float* __restrict__ kern,
                                              const float* __restrict__ dis,
                                              float* __restrict__ h2, int n) {
    __shared__ __align__(16) float ks[64 * 64];
    __shared__ float xs[32 * 65];
    int t = threadIdx.x;

    const float4* k4 = (const float4*)kern;
    float4* ks4 = (float4*)ks;
    #pragma unroll
    for (int i = 0; i < 4; ++i) ks4[t + i * 256] = k4[t + i * 256];

    int r0 = blockIdx.x * 32;
    #pragma unroll
    for (int p = 0; p < 2; ++p) {
        int rr = (t >> 4) + p * 16;
        int cc = (t & 15) * 4;
        int gr = r0 + rr;
        float4 xv = make_float4(0.f, 0.f, 0.f, 0.f);
        if (gr < n) xv = *(const float4*)(x + (size_t)gr * 64 + cc);
        xs[rr * 65 + cc + 0] = xv.x;
        xs[rr * 65 + cc + 1] = xv.y;
        xs[rr * 65 + cc + 2] = xv.z;
        xs[rr * 65 + cc + 3] = xv.w;
    }
    __syncthreads();

    int rg = t >> 4;
    int ug = t & 15;
    int ra = 2 * rg, rb = 2 * rg + 1;
    float4 a0 = make_float4(0.f, 0.f, 0.f, 0.f);
    float4 a1 = make_float4(0.f, 0.f, 0.f, 0.f);
    #pragma unroll
    for (int k = 0; k < 64; ++k) {
        float xa = xs[ra * 65 + k];
        float xb = xs[rb * 65 + k];
        float4 kv = *(const float4*)(ks + k * 64 + 4 * ug);
        a0.x = fmaf(xa, kv.x, a0.x); a0.y = fmaf(xa, kv.y, a0.y);
        a0.z = fmaf(xa, kv.z, a0.z); a0.w = fmaf(xa, kv.w, a0.w);
        a1.x = fmaf(xb, kv.x, a1.x); a1.y = fmaf(xb, kv.y, a1.y);
        a1.z = fmaf(xb, kv.z, a1.z); a1.w = fmaf(xb, kv.w, a1.w);
    }
    int gra = r0 + ra, grb = r0 + rb;
    if (gra < n) {
        float d = dis[gra];
        *(float4*)(h2 + (size_t)gra * 64 + 4 * ug) =
            make_float4(d * a0.x, d * a0.y, d * a0.z, d * a0.w);
    }
    if (grb < n) {
        float d = dis[grb];
        *(float4*)(h2 + (size_t)grb * 64 + 4 * ug) =
            make_float4(d * a1.x, d * a1.y, d * a1.z, d * a1.w);
    }
}

// ---------------- pull: one wave per node ----------------

__global__ __launch_bounds__(256) void k_pull(const int* __restrict__ start,
                                              const u64* __restrict__ edges,
                                              const float* __restrict__ h2,
                                              const float* __restrict__ dis,
                                              const float* __restrict__ bias,
                                              float* __restrict__ out, int N) {
    int node = (blockIdx.x << 2) + (threadIdx.x >> 6);
    int lane = threadIdx.x & 63;
    if (node >= N) return;
    int s = start[node], epos = start[node + 1];
    float acc = 0.f;
    for (int base = s; base < epos; base += 64) {
        int n = epos - base;
        if (n > 64) n = 64;
        int cl = 0; int vl = 0;
        if (lane < n) {
            u64 p = edges[base + lane];
            cl = (int)((unsigned)p & 0xFFFFFF);
            vl = (int)(unsigned)(p >> 32);
        }
        int j = 0;
        for (; j + 4 <= n; j += 4) {
            int c0 = __shfl(cl, j),     c1 = __shfl(cl, j + 1);
            int c2 = __shfl(cl, j + 2), c3 = __shfl(cl, j + 3);
            float v0 = __uint_as_float((unsigned)__shfl(vl, j));
            float v1 = __uint_as_float((unsigned)__shfl(vl, j + 1));
            float v2 = __uint_as_float((unsigned)__shfl(vl, j + 2));
            float v3 = __uint_as_float((unsigned)__shfl(vl, j + 3));
            float g0 = h2[(size_t)c0 * 64 + lane];
            float g1 = h2[(size_t)c1 * 64 + lane];
            float g2 = h2[(size_t)c2 * 64 + lane];
            float g3 = h2[(size_t)c3 * 64 + lane];
            acc = fmaf(v0, g0, acc);
            acc = fmaf(v1, g1, acc);
            acc = fmaf(v2, g2, acc);
            acc = fmaf(v3, g3, acc);
        }
        for (; j < n; ++j) {
            int c = __shfl(cl, j);
            float v = __uint_as_float((unsigned)__shfl(vl, j));
            acc = fmaf(v, h2[(size_t)c * 64 + lane], acc);
        }
    }
    float di = dis[node];
    out[(size_t)node * 64 + lane] =
        di * acc + FILL * di * h2[(size_t)node * 64 + lane] + bias[lane];
}

// ---------------- fallback (atomic scatter) ----------------

__global__ void k_fb_deg_init(float* __restrict__ deg, int n) {
    int i = blockIdx.x * blockDim.x + threadIdx.x;
    if (i < n) deg[i] = FILL;
}
__global__ void k_fb_deg_edges(const int* __restrict__ row, const float* __restrict__ w,
                               float* __restrict__ deg, int E) {
    int e = blockIdx.x * blockDim.x + threadIdx.x;
    if (e < E) atomicAdd(&deg[row[e]], w[e]);
}
__global__ void k_fb_dis(const float* __restrict__ deg, float* __restrict__ dis, int n) {
    int i = blockIdx.x * blockDim.x + threadIdx.x;
    if (i < n) {
        float d = deg[i];
        dis[i] = (d > 0.f) ? rsqrtf(fmaxf(d, 1e-12f)) : 0.f;
    }
}
__global__ void k_fb_outinit(const float* __restrict__ h2, const float* __restrict__ dis,
                             const float* __restrict__ bias, float* __restrict__ out, int n) {
    int t = blockIdx.x * blockDim.x + threadIdx.x;
    if (t < n * 64) {
        int i = t >> 6, u = t & 63;
        out[t] = FILL * dis[i] * h2[t] + bias[u];
    }
}
__global__ __launch_bounds__(256) void k_fb_scatter(const int* __restrict__ row,
                                                    const int* __restrict__ col,
                                                    const float* __restrict__ w,
                                                    const float* __restrict__ dis,
                                                    const float* __restrict__ h2,
                                                    float* __restrict__ out, int E) {
    long long t = (long long)blockIdx.x * blockDim.x + threadIdx.x;
    int e = (int)(t >> 4);
    int j = (int)(t & 15);
    if (e < E) {
        int r = row[e], c = col[e];
        float nw = dis[r] * w[e];
        float4 hv = reinterpret_cast<const float4*>(h2 + (long long)c * 64)[j];
        float* op = out + (long long)r * 64 + j * 4;
        atomicAdd(op + 0, hv.x * nw);
        atomicAdd(op + 1, hv.y * nw);
        atomicAdd(op + 2, hv.z * nw);
        atomicAdd(op + 3, hv.w * nw);
    }
}

// ---------------- launch ----------------

extern "C" void kernel_launch(void* const* d_in, const int* in_sizes, int n_in,
                              void* d_out, int out_size, void* d_ws, size_t ws_size,
                              hipStream_t stream) {
    const float* x    = (const float*)d_in[0];
    const int*   ei   = (const int*)d_in[1];
    const float* ew   = (const float*)d_in[2];
    const float* kern = (const float*)d_in[3];
    const float* bias = (const float*)d_in[4];
    float* out = (float*)d_out;

    int N = in_sizes[0] / 64;
    int E = in_sizes[1] / 2;
    const int* row = ei;
    const int* col = ei + E;

    const int B = 256;
    int NB = (N + BKN - 1) >> SB;

    size_t need = (size_t)E * 8 * 2           // eA, eB
                + (size_t)N * 64 * 4          // h2
                + (size_t)N * 4               // dis
                + (size_t)(N + 1) * 4         // start
                + (size_t)(3 * NB + 1) * 4;   // bcnt, bstart[NB+1], bcur

    if (ws_size >= need && NB <= 512 && N <= (1 << 24)) {
        char* p = (char*)d_ws;
        u64*   eA    = (u64*)p;            p += (size_t)E * 8;
        u64*   eB    = (u64*)p;            p += (size_t)E * 8;
        float* h2    = (float*)p;          p += (size_t)N * 64 * 4;
        float* dis   = (float*)p;          p += (size_t)N * 4;
        int*   start = (int*)p;            p += (size_t)(N + 1) * 4;
        int*   bcnt  = (int*)p;            p += (size_t)NB * 4;
        int*   bstart= (int*)p;            p += (size_t)(NB + 1) * 4;
        int*   bcur  = (int*)p;

        int nt = (E + 4095) >> 12;
        k_zero<<<(NB + B - 1) / B, B, 0, stream>>>(bcnt, NB);
        k_bhist<<<1024, B, 0, stream>>>(row, bcnt, E, NB);
        k_bscan<<<1, 512, 0, stream>>>(bcnt, bstart, bcur, start, NB, N, E);
        k_bscatter<<<nt, B, 0, stream>>>(row, col, ew, bcur, eA, E, NB);
        k_fine<<<NB, B, 0, stream>>>(bstart, eA, eB, start, dis, N);
        k_gemm<<<(N + 31) / 32, B, 0, stream>>>(x, kern, dis, h2, N);
        k_pull<<<(N + 3) / 4, B, 0, stream>>>(start, eB, h2, dis, bias, out, N);
    } else {
        // fallback: atomic scatter
        char* p = (char*)d_ws;
        float* h2  = (float*)p;  p += (size_t)N * 64 * 4;
        float* deg = (float*)p;  p += (size_t)N * 4;
        float* dis = (float*)p;

        k_fb_deg_init<<<(N + B - 1) / B, B, 0, stream>>>(deg, N);
        k_fb_deg_edges<<<(E + B - 1) / B, B, 0, stream>>>(row, ew, deg, E);
        k_fb_dis<<<(N + B - 1) / B, B, 0, stream>>>(deg, dis, N);
        k_gemm<<<(N + 31) / 32, B, 0, stream>>>(x, kern, dis, h2, N);
        k_fb_outinit<<<((long long)N * 64 + B - 1) / B, B, 0, stream>>>(h2, dis, bias, out, N);
        long long st = (long long)E * 16;
        k_fb_scatter<<<(st + B - 1) / B, B, 0, stream>>>(row, col, ew, dis, h2, out, E);
    }
}

// Round 4
// 170.117 us; speedup vs baseline: 8.8601x; 1.1423x over previous
//
#include <hip/hip_runtime.h>

// GCN layer: out = D^-1/2 (A + I) D^-1/2 (x @ kernel) + bias
// N=100000, E=1600000, F=U=64, fp32 in/out; h2 staged as bf16.
// Pipeline: two-level counting sort by destination, pull aggregation.

typedef unsigned long long u64;
#define FILL 1.0f
#define SB 8
#define BKN 256
#define EPT 16

__device__ inline unsigned bf16rne(float f) {
    unsigned u = __float_as_uint(f);
    return (u + 0x7FFFu + ((u >> 16) & 1u)) >> 16;
}
__device__ inline unsigned pack2(float lo, float hi) {
    return bf16rne(lo) | (bf16rne(hi) << 16);
}
__device__ inline float unlo(unsigned g) { return __uint_as_float(g << 16); }
__device__ inline float unhi(unsigned g) { return __uint_as_float(g & 0xFFFF0000u); }

// ---------------- phase 1: bucket histogram + scan ----------------

__global__ void k_zero(int* __restrict__ p, int n) {
    int i = blockIdx.x * blockDim.x + threadIdx.x;
    if (i < n) p[i] = 0;
}

__global__ __launch_bounds__(256) void k_bhist(const int* __restrict__ row,
                                               int* __restrict__ bcnt, int E, int NB) {
    __shared__ int h[512];
    for (int i = threadIdx.x; i < NB; i += 256) h[i] = 0;
    __syncthreads();
    int stride = gridDim.x * 256;
    for (int e = blockIdx.x * 256 + threadIdx.x; e < E; e += stride)
        atomicAdd(&h[row[e] >> SB], 1);
    __syncthreads();
    for (int i = threadIdx.x; i < NB; i += 256)
        if (h[i]) atomicAdd(&bcnt[i], h[i]);
}

__global__ __launch_bounds__(512) void k_bscan(const int* __restrict__ bcnt,
                                               int* __restrict__ bstart, int* __restrict__ bcur,
                                               int* __restrict__ start, int NB, int N, int E) {
    __shared__ int a[512], bsh[512];
    int t = threadIdx.x;
    a[t] = (t < NB) ? bcnt[t] : 0;
    __syncthreads();
    int *src = a, *dst = bsh;
    for (int o = 1; o < 512; o <<= 1) {
        int v = src[t];
        if (t >= o) v += src[t - o];
        dst[t] = v;
        __syncthreads();
        int* tm = src; src = dst; dst = tm;
    }
    int incl = src[t];
    if (t < NB) {
        int excl = incl - bcnt[t];
        bstart[t] = excl;
        bcur[t] = excl;
    }
    if (t == NB - 1) bstart[NB] = incl;
    if (t == 0) start[N] = E;
}

// ---------------- phase 2: tile-reserved bucket scatter ----------------
// record: w(63..32) | row_local(31..24) | col(23..0)

__global__ __launch_bounds__(256) void k_bscatter(const int* __restrict__ row,
                                                  const int* __restrict__ col,
                                                  const float* __restrict__ w,
                                                  int* __restrict__ bcur,
                                                  u64* __restrict__ eA, int E, int NB) {
    __shared__ int cnt[512];
    __shared__ int ofs[512];
    int nt = (E + 4095) >> 12;
    for (int tile = blockIdx.x; tile < nt; tile += gridDim.x) {
        int base = tile << 12;
        for (int i = threadIdx.x; i < NB; i += 256) cnt[i] = 0;
        __syncthreads();
        int bk[EPT]; u64 rec[EPT];
        #pragma unroll
        for (int k = 0; k < EPT; ++k) {
            int e = base + threadIdx.x + (k << 8);
            bk[k] = -1;
            if (e < E) {
                int r = row[e];
                bk[k] = r >> SB;
                rec[k] = ((u64)__float_as_uint(w[e]) << 32)
                       | ((u64)(unsigned)(r & (BKN - 1)) << 24)
                       | (u64)(unsigned)col[e];
                atomicAdd(&cnt[bk[k]], 1);
            }
        }
        __syncthreads();
        for (int i = threadIdx.x; i < NB; i += 256) {
            int c = cnt[i];
            ofs[i] = c ? atomicAdd(&bcur[i], c) : 0;
            cnt[i] = 0;
        }
        __syncthreads();
        #pragma unroll
        for (int k = 0; k < EPT; ++k) {
            if (bk[k] >= 0) {
                int pos = ofs[bk[k]] + atomicAdd(&cnt[bk[k]], 1);
                eA[pos] = rec[k];
            }
        }
        __syncthreads();
    }
}

// ---------------- phase 3: exact sort within bucket + start + dis ----------------

__global__ __launch_bounds__(256) void k_fine(const int* __restrict__ bstart,
                                              const u64* __restrict__ eA,
                                              u64* __restrict__ eB,
                                              int* __restrict__ start,
                                              float* __restrict__ dis, int N) {
    __shared__ int ncnt[256];
    __shared__ float degs[256];
    __shared__ int sa[256], sb[256];
    int b = blockIdx.x;
    int s = bstart[b], e1 = bstart[b + 1];
    int cnt = e1 - s;
    int t = threadIdx.x;
    ncnt[t] = 0;
    degs[t] = 0.f;
    __syncthreads();
    for (int i = t; i < cnt; i += 256) {
        u64 p = eA[s + i];
        int rl = (int)((p >> 24) & 0xFF);
        atomicAdd(&ncnt[rl], 1);
        atomicAdd(&degs[rl], __uint_as_float((unsigned)(p >> 32)));
    }
    __syncthreads();
    int c = ncnt[t];
    sa[t] = c;
    __syncthreads();
    int *src = sa, *dst = sb;
    for (int o = 1; o < 256; o <<= 1) {
        int v = src[t];
        if (t >= o) v += src[t - o];
        dst[t] = v;
        __syncthreads();
        int* tm = src; src = dst; dst = tm;
    }
    int excl = src[t] - c;
    int node = (b << SB) + t;
    if (node < N) {
        start[node] = s + excl;
        float d = FILL + degs[t];
        dis[node] = (d > 0.f) ? rsqrtf(fmaxf(d, 1e-12f)) : 0.f;
    }
    ncnt[t] = excl;
    __syncthreads();
    for (int i = t; i < cnt; i += 256) {
        u64 p = eA[s + i];
        int rl = (int)((p >> 24) & 0xFF);
        int pos = atomicAdd(&ncnt[rl], 1);
        eB[s + pos] = p & 0xFFFFFFFF00FFFFFFULL;
    }
}

// ---------------- h2b = bf16( dis[r] * (x @ kernel) ) ----------------
// 64 rows/block; thread = 4 rows x 4 units; all-b128 LDS traffic.

__global__ __launch_bounds__(256) void k_gemm(const float* __restrict__ x,
                                              const float* __restrict__ kern,
                                              const float* __restrict__ dis,
                                              unsigned* __restrict__ h2b, int n) {
    __shared__ __align__(16) float ks[64 * 64];
    __shared__ __align__(16) float xs[64 * 68];
    int t = threadIdx.x;

    const float4* k4g = (const float4*)kern;
    float4* ks4 = (float4*)ks;
    #pragma unroll
    for (int i = 0; i < 4; ++i) ks4[t + i * 256] = k4g[t + i * 256];

    int r0 = blockIdx.x * 64;
    #pragma unroll
    for (int i = 0; i < 4; ++i) {
        int idx = t + i * 256;          // float4 index 0..1023
        int rr = idx >> 4;
        int c4 = (idx & 15) << 2;
        int gr = r0 + rr;
        float4 v = make_float4(0.f, 0.f, 0.f, 0.f);
        if (gr < n) v = *(const float4*)(x + (size_t)gr * 64 + c4);
        *(float4*)(xs + rr * 68 + c4) = v;
    }
    __syncthreads();

    int rg = t >> 4;   // rows rg*4 .. rg*4+3
    int ug = t & 15;   // units ug*4 .. ug*4+3
    float4 acc[4];
    #pragma unroll
    for (int r = 0; r < 4; ++r) acc[r] = make_float4(0.f, 0.f, 0.f, 0.f);

    #pragma unroll 2
    for (int kk = 0; kk < 16; ++kk) {
        float4 wv0 = *(const float4*)(ks + (kk * 4 + 0) * 64 + ug * 4);
        float4 wv1 = *(const float4*)(ks + (kk * 4 + 1) * 64 + ug * 4);
        float4 wv2 = *(const float4*)(ks + (kk * 4 + 2) * 64 + ug * 4);
        float4 wv3 = *(const float4*)(ks + (kk * 4 + 3) * 64 + ug * 4);
        #pragma unroll
        for (int r = 0; r < 4; ++r) {
            float4 xv = *(const float4*)(xs + (rg * 4 + r) * 68 + kk * 4);
            acc[r].x = fmaf(xv.x, wv0.x, acc[r].x);
            acc[r].y = fmaf(xv.x, wv0.y, acc[r].y);
            acc[r].z = fmaf(xv.x, wv0.z, acc[r].z);
            acc[r].w = fmaf(xv.x, wv0.w, acc[r].w);
            acc[r].x = fmaf(xv.y, wv1.x, acc[r].x);
            acc[r].y = fmaf(xv.y, wv1.y, acc[r].y);
            acc[r].z = fmaf(xv.y, wv1.z, acc[r].z);
            acc[r].w = fmaf(xv.y, wv1.w, acc[r].w);
            acc[r].x = fmaf(xv.z, wv2.x, acc[r].x);
            acc[r].y = fmaf(xv.z, wv2.y, acc[r].y);
            acc[r].z = fmaf(xv.z, wv2.z, acc[r].z);
            acc[r].w = fmaf(xv.z, wv2.w, acc[r].w);
            acc[r].x = fmaf(xv.w, wv3.x, acc[r].x);
            acc[r].y = fmaf(xv.w, wv3.y, acc[r].y);
            acc[r].z = fmaf(xv.w, wv3.z, acc[r].z);
            acc[r].w = fmaf(xv.w, wv3.w, acc[r].w);
        }
    }

    #pragma unroll
    for (int r = 0; r < 4; ++r) {
        int gr = r0 + rg * 4 + r;
        if (gr < n) {
            float d = dis[gr];
            unsigned u0 = pack2(d * acc[r].x, d * acc[r].y);
            unsigned u1 = pack2(d * acc[r].z, d * acc[r].w);
            uint2 uu; uu.x = u0; uu.y = u1;
            *(uint2*)(h2b + (size_t)gr * 32 + ug * 2) = uu;
        }
    }
}

// ---------------- pull: one wave per node, 2 edges x 32 lanes x bf16x2 ----------------

__global__ __launch_bounds__(256) void k_pull(const int* __restrict__ start,
                                              const u64* __restrict__ edges,
                                              const unsigned* __restrict__ h2b,
                                              const float* __restrict__ dis,
                                              const float* __restrict__ bias,
                                              float* __restrict__ out, int N) {
    int node = (blockIdx.x << 2) + (threadIdx.x >> 6);
    int lane = threadIdx.x & 63;
    if (node >= N) return;
    int s = start[node], e1 = start[node + 1];
    int eh = lane >> 5;   // edge slot within pair
    int up = lane & 31;   // unit pair -> units 2up, 2up+1
    float a0 = 0.f, a1 = 0.f;
    for (int base = s; base < e1; base += 64) {
        int nn = e1 - base; if (nn > 64) nn = 64;
        int cl = 0, vl = 0;
        if (lane < nn) {
            u64 p = edges[base + lane];
            cl = (int)((unsigned)p & 0xFFFFFF);
            vl = (int)(unsigned)(p >> 32);
        }
        for (int j = 0; j < nn; j += 2) {
            int jj = j + eh;
            int sj = (jj < nn) ? jj : (nn - 1);
            int c = __shfl(cl, sj);
            float v = __uint_as_float((unsigned)__shfl(vl, sj));
            if (jj >= nn) v = 0.f;
            unsigned g = h2b[(size_t)c * 32 + up];
            a0 = fmaf(v, unlo(g), a0);
            a1 = fmaf(v, unhi(g), a1);
        }
    }
    a0 += __shfl_xor(a0, 32);
    a1 += __shfl_xor(a1, 32);
    if (eh == 0) {
        float di = dis[node];
        unsigned gs = h2b[(size_t)node * 32 + up];
        float2 bv = *(const float2*)(bias + 2 * up);
        float2 o;
        o.x = di * a0 + FILL * di * unlo(gs) + bv.x;
        o.y = di * a1 + FILL * di * unhi(gs) + bv.y;
        *(float2*)(out + (size_t)node * 64 + 2 * up) = o;
    }
}

// ---------------- fallback (atomic scatter) ----------------

__global__ void k_fb_deg_init(float* __restrict__ deg, int n) {
    int i = blockIdx.x * blockDim.x + threadIdx.x;
    if (i < n) deg[i] = FILL;
}
__global__ void k_fb_deg_edges(const int* __restrict__ row, const float* __restrict__ w,
                               float* __restrict__ deg, int E) {
    int e = blockIdx.x * blockDim.x + threadIdx.x;
    if (e < E) atomicAdd(&deg[row[e]], w[e]);
}
__global__ void k_fb_dis(const float* __restrict__ deg, float* __restrict__ dis, int n) {
    int i = blockIdx.x * blockDim.x + threadIdx.x;
    if (i < n) {
        float d = deg[i];
        dis[i] = (d > 0.f) ? rsqrtf(fmaxf(d, 1e-12f)) : 0.f;
    }
}
__global__ void k_fb_outinit(const unsigned* __restrict__ h2b, const float* __restrict__ dis,
                             const float* __restrict__ bias, float* __restrict__ out, int n) {
    int t = blockIdx.x * blockDim.x + threadIdx.x;
    if (t < n * 64) {
        int i = t >> 6, u = t & 63;
        unsigned g = h2b[(size_t)i * 32 + (u >> 1)];
        float hv = (u & 1) ? unhi(g) : unlo(g);
        out[t] = FILL * dis[i] * hv + bias[u];
    }
}
__global__ __launch_bounds__(256) void k_fb_scatter(const int* __restrict__ row,
                                                    const int* __restrict__ col,
                                                    const float* __restrict__ w,
                                                    const float* __restrict__ dis,
                                                    const unsigned* __restrict__ h2b,
                                                    float* __restrict__ out, int E) {
    long long t = (long long)blockIdx.x * blockDim.x + threadIdx.x;
    int e = (int)(t >> 4);
    int j = (int)(t & 15);
    if (e < E) {
        int r = row[e], c = col[e];
        float nw = dis[r] * w[e];
        uint2 g2 = *(const uint2*)(h2b + (size_t)c * 32 + 2 * j);
        float* op = out + (long long)r * 64 + j * 4;
        atomicAdd(op + 0, unlo(g2.x) * nw);
        atomicAdd(op + 1, unhi(g2.x) * nw);
        atomicAdd(op + 2, unlo(g2.y) * nw);
        atomicAdd(op + 3, unhi(g2.y) * nw);
    }
}

// ---------------- launch ----------------

extern "C" void kernel_launch(void* const* d_in, const int* in_sizes, int n_in,
                              void* d_out, int out_size, void* d_ws, size_t ws_size,
                              hipStream_t stream) {
    const float* x    = (const float*)d_in[0];
    const int*   ei   = (const int*)d_in[1];
    const float* ew   = (const float*)d_in[2];
    const float* kern = (const float*)d_in[3];
    const float* bias = (const float*)d_in[4];
    float* out = (float*)d_out;

    int N = in_sizes[0] / 64;
    int E = in_sizes[1] / 2;
    const int* row = ei;
    const int* col = ei + E;

    const int B = 256;
    int NB = (N + BKN - 1) >> SB;

    size_t need = (size_t)E * 8 * 2           // eA, eB
                + (size_t)N * 128             // h2b (bf16)
                + (size_t)N * 4               // dis
                + (size_t)(N + 1) * 4         // start
                + (size_t)(3 * NB + 1) * 4;

    if (ws_size >= need && NB <= 512 && N <= (1 << 24)) {
        char* p = (char*)d_ws;
        u64*      eA    = (u64*)p;         p += (size_t)E * 8;
        u64*      eB    = (u64*)p;         p += (size_t)E * 8;
        unsigned* h2b   = (unsigned*)p;    p += (size_t)N * 128;
        float*    dis   = (float*)p;       p += (size_t)N * 4;
        int*      start = (int*)p;         p += (size_t)(N + 1) * 4;
        int*      bcnt  = (int*)p;         p += (size_t)NB * 4;
        int*      bstart= (int*)p;         p += (size_t)(NB + 1) * 4;
        int*      bcur  = (int*)p;

        int nt = (E + 4095) >> 12;
        k_zero<<<(NB + B - 1) / B, B, 0, stream>>>(bcnt, NB);
        k_bhist<<<1024, B, 0, stream>>>(row, bcnt, E, NB);
        k_bscan<<<1, 512, 0, stream>>>(bcnt, bstart, bcur, start, NB, N, E);
        k_bscatter<<<nt, B, 0, stream>>>(row, col, ew, bcur, eA, E, NB);
        k_fine<<<NB, B, 0, stream>>>(bstart, eA, eB, start, dis, N);
        k_gemm<<<(N + 63) / 64, B, 0, stream>>>(x, kern, dis, h2b, N);
        k_pull<<<(N + 3) / 4, B, 0, stream>>>(start, eB, h2b, dis, bias, out, N);
    } else {
        char* p = (char*)d_ws;
        unsigned* h2b = (unsigned*)p;  p += (size_t)N * 128;
        float*    deg = (float*)p;     p += (size_t)N * 4;
        float*    dis = (float*)p;

        k_fb_deg_init<<<(N + B - 1) / B, B, 0, stream>>>(deg, N);
        k_fb_deg_edges<<<(E + B - 1) / B, B, 0, stream>>>(row, ew, deg, E);
        k_fb_dis<<<(N + B - 1) / B, B, 0, stream>>>(deg, dis, N);
        k_gemm<<<(N + 63) / 64, B, 0, stream>>>(x, kern, dis, h2b, N);
        k_fb_outinit<<<((long long)N * 64 + B - 1) / B, B, 0, stream>>>(h2b, dis, bias, out, N);
        long long st = (long long)E * 16;
        k_fb_scatter<<<(st + B - 1) / B, B, 0, stream>>>(row, col, ew, dis, h2b, out, E);
    }
}